// Round 6
// baseline (223.172 us; speedup 1.0000x reference)
//
#include <hip/hip_runtime.h>
#include <stdint.h>

// All I/O fp32. MFMA bf16: weights as A-operand (A[m=out][k]), activations as
// B (B[k][n=point]); next layer's weights pre-permuted along input dim
// (P(k)=4*(k>>3)+(k&3)+16*((k>>2)&1)) so layer->layer handoff is in-lane packs.
// R6: residency split. Chain frags (13) + biases in explicit VGPRs (loaded once
// per wave); bank frags (16, independent MFMAs) in LDS; 3-op bf16 pack via
// v_perm_b32 (half-up; differs from RTNE only on exact ties).

typedef __attribute__((ext_vector_type(8))) __bf16 bf16x8;
typedef __attribute__((ext_vector_type(4))) float f32x4;

union FragU { uint32_t u[4]; bf16x8 v; uint4 q; };

__device__ __forceinline__ unsigned short f2bf(float f) {
    union { float f; uint32_t i; } v; v.f = f;
    return (unsigned short)((v.i + 0x7FFFu + ((v.i >> 16) & 1u)) >> 16); // RTNE (prep only)
}
__device__ __forceinline__ float bf2f(uint32_t u16) {
    union { uint32_t i; float f; } v; v.i = u16 << 16; return v.f;
}
// fast pack: lo16 = bf16(x), hi16 = bf16(y); round-half-up (3 VALU)
__device__ __forceinline__ uint32_t pk2f(float x, float y) {
    union { float f; uint32_t i; } a, b; a.f = x; b.f = y;
    return __builtin_amdgcn_perm(b.i + 0x8000u, a.i + 0x8000u, 0x07060302u);
}
__device__ __forceinline__ int permK(int k) {
    return 4 * (k >> 3) + (k & 3) + 16 * ((k >> 2) & 1);
}
__device__ __forceinline__ f32x4 MF(bf16x8 a, bf16x8 b, f32x4 c) {
    return __builtin_amdgcn_mfma_f32_16x16x32_bf16(a, b, c, 0, 0, 0);
}

// ws dword layout (10240 dwords):
//   [0,1024)    layer0 A-frags  [chunk(2)][tile(2)][lane(64)][dw(4)]  (K=60 pad 64)
//   [1024,3072) layers1-4 A     [L(4)][tile(2)][lane][dw]             (perm k)
//   [3072,3328) layer5 A        [lane][dw]                            (perm k, m>=8 zero)
//   [3328,7424) bank A          [k(8)][tile(2)][lane][dw]
//   [7424,9984) bias L0-4 fp32  [L(5)][tile(2)][lane][r(4)]
//   [9984,10240) bias L5 fp32   [lane][r]                             (m>=8 zero)

struct WPf { const float* p[13]; };

__global__ void pc_prep(WPf wp, uint32_t* __restrict__ ws) {
    int idx = blockIdx.x * blockDim.x + threadIdx.x;
    if (idx >= 10240) return;
    if (idx < 7424) {
        int layer, t, chunk = 0, lane, d; const float* w; bool perm;
        int r = idx;
        if (r < 1024) { chunk = r >> 9; r &= 511; t = r >> 8; r &= 255; lane = r >> 2; d = r & 3;
                        layer = 0; w = wp.p[0]; perm = false; }
        else if (r < 3072) { r -= 1024; layer = 1 + (r >> 9); r &= 511; t = r >> 8; r &= 255;
                             lane = r >> 2; d = r & 3; w = wp.p[2 * layer]; perm = true; }
        else if (r < 3328) { r -= 3072; layer = 5; t = 0; lane = r >> 2; d = r & 3;
                             w = wp.p[10]; perm = true; }
        else { r -= 3328; int bk = r >> 9; r &= 511; t = r >> 8; r &= 255; lane = r >> 2; d = r & 3;
               layer = -1; w = wp.p[12] + bk * 1024; perm = false; }
        int gq = lane >> 4, m = t * 16 + (lane & 15);
        uint32_t o = 0;
        #pragma unroll
        for (int e = 0; e < 2; ++e) {
            int kf = 8 * gq + 2 * d + e;
            float v = 0.f;
            if (layer == -1) {
                v = w[kf * 32 + m];                       // bank: A[m=o][k=i] = bank[k][i*32+o]
            } else {
                int ks = perm ? permK(kf) : (chunk * 32 + kf);
                if (layer == 0)      { if (ks < 60) v = w[ks * 32 + m]; }
                else if (layer == 5) { if (m < 8)   v = w[ks * 8 + m]; }
                else                 v = w[ks * 32 + m];  // A[m][k] = W[P(k)][m]
            }
            o |= ((uint32_t)f2bf(v)) << (16 * e);
        }
        ws[idx] = o;
    } else if (idx < 9984) {
        int r = idx - 7424; int L = r >> 9; r &= 511; int t = r >> 8; r &= 255;
        int lane = r >> 2, rr = r & 3;
        ((float*)ws)[idx] = wp.p[2 * L + 1][t * 16 + 4 * (lane >> 4) + rr];
    } else {
        int r = idx - 9984; int lane = r >> 2, rr = r & 3;
        int m = 4 * (lane >> 4) + rr;
        ((float*)ws)[idx] = (m < 8) ? wp.p[11][m] : 0.f;
    }
}

#define IT 4   // 16 pts/iter * IT * 4 waves = 256 pts/block; 1024 blocks

__global__ __launch_bounds__(256, 3) void pc_main(
    const float* __restrict__ rel, const float* __restrict__ feat,
    const uint32_t* __restrict__ wsu, float* __restrict__ out)
{
    __shared__ __align__(16) uint32_t WB[4096];   // 16 KB: bank frags only
    {
        uint4* s4 = (uint4*)WB;
        const uint4* g4 = (const uint4*)wsu + 832;   // bank at dword 3328
        #pragma unroll
        for (int i = 0; i < 4; ++i) s4[threadIdx.x + 256 * i] = g4[threadIdx.x + 256 * i];
    }
    __syncthreads();

    const int lane = threadIdx.x & 63;
    const int wv = threadIdx.x >> 6;
    const int g = lane >> 4;
    const int n16 = lane & 15;

    #define LDG(off) ({ FragU _f; _f.q = ((const uint4*)(wsu + (off)))[lane]; _f.v; })
    // chain weight frags: resident in VGPRs for the whole wave (52 VGPR)
    const bf16x8 A00 = LDG(0),   A01 = LDG(256);
    const bf16x8 A10 = LDG(512), A11 = LDG(768);
    bf16x8 A14[4][2];
    #pragma unroll
    for (int L = 0; L < 4; ++L) {
        A14[L][0] = LDG(1024 + L * 512);
        A14[L][1] = LDG(1024 + L * 512 + 256);
    }
    const bf16x8 A5 = LDG(3072);
    #undef LDG

    // biases resident (44 VGPR)
    const float* bw = (const float*)wsu;
    f32x4 Bi[5][2], Bi5;
    #pragma unroll
    for (int L = 0; L < 5; ++L)
        #pragma unroll
        for (int t = 0; t < 2; ++t) {
            float4 b = ((const float4*)(bw + 7424 + L * 512 + t * 256))[lane];
            Bi[L][t][0] = b.x; Bi[L][t][1] = b.y; Bi[L][t][2] = b.z; Bi[L][t][3] = b.w;
        }
    {
        float4 b = ((const float4*)(bw + 9984))[lane];
        Bi5[0] = b.x; Bi5[1] = b.y; Bi5[2] = b.z; Bi5[3] = b.w;
    }

    const size_t pt0 = (size_t)(blockIdx.x * 4 + wv) * (16 * IT);

    #define LDS_F(off) ({ FragU _f; _f.q = ((const uint4*)(WB + (off)))[lane]; _f.v; })

    #pragma unroll 2
    for (int it = 0; it < IT; ++it) {
        const size_t n = pt0 + (size_t)it * 16 + n16;

        // ---- inputs (independent; issue together at iter head) ----
        const float* rrow = rel + n * 60;
        float4 ra = *(const float4*)(rrow + 8 * g);
        float4 rb = *(const float4*)(rrow + 8 * g + 4);
        float4 rc = *(const float4*)(rrow + 32 + 8 * g);
        float4 rd = make_float4(0.f, 0.f, 0.f, 0.f);
        if (g < 3) rd = *(const float4*)(rrow + 36 + 8 * g);
        const float* frow = feat + n * 32 + 8 * g;
        float4 fa = *(const float4*)frow;
        float4 fb = *(const float4*)(frow + 4);

        FragU b0, b1;
        b0.u[0] = pk2f(ra.x, ra.y); b0.u[1] = pk2f(ra.z, ra.w);
        b0.u[2] = pk2f(rb.x, rb.y); b0.u[3] = pk2f(rb.z, rb.w);
        b1.u[0] = pk2f(rc.x, rc.y); b1.u[1] = pk2f(rc.z, rc.w);
        b1.u[2] = pk2f(rd.x, rd.y); b1.u[3] = pk2f(rd.z, rd.w);

        // ---- layer 0 ----
        f32x4 t0 = Bi[0][0], t1 = Bi[0][1];
        t0 = MF(A00, b0.v, t0); t1 = MF(A01, b0.v, t1);
        t0 = MF(A10, b1.v, t0); t1 = MF(A11, b1.v, t1);

        // ---- layers 1..4 ----
        #pragma unroll
        for (int L = 0; L < 4; ++L) {
            FragU bx;
            #pragma unroll
            for (int r = 0; r < 4; ++r) {
                t0[r] = fmaxf(t0[r], 0.01f * t0[r]);
                t1[r] = fmaxf(t1[r], 0.01f * t1[r]);
            }
            bx.u[0] = pk2f(t0[0], t0[1]); bx.u[1] = pk2f(t0[2], t0[3]);
            bx.u[2] = pk2f(t1[0], t1[1]); bx.u[3] = pk2f(t1[2], t1[3]);
            t0 = MF(A14[L][0], bx.v, Bi[L + 1][0]);
            t1 = MF(A14[L][1], bx.v, Bi[L + 1][1]);
        }

        // ---- layer 5 (32->8) ----
        {
            FragU bx;
            #pragma unroll
            for (int r = 0; r < 4; ++r) {
                t0[r] = fmaxf(t0[r], 0.01f * t0[r]);
                t1[r] = fmaxf(t1[r], 0.01f * t1[r]);
            }
            bx.u[0] = pk2f(t0[0], t0[1]); bx.u[1] = pk2f(t0[2], t0[3]);
            bx.u[2] = pk2f(t1[0], t1[1]); bx.u[3] = pk2f(t1[2], t1[3]);
            t0 = MF(A5, bx.v, Bi5);   // logits m0..3 in g=0, m4..7 in g=1
        }

        // ---- softmax over 8 (lane pair n16 / n16+16 via xor-16) ----
        float m4 = fmaxf(fmaxf(t0[0], t0[1]), fmaxf(t0[2], t0[3]));
        float m8 = fmaxf(m4, __shfl_xor(m4, 16, 64));
        float e0 = __expf(t0[0] - m8), e1 = __expf(t0[1] - m8);
        float e2 = __expf(t0[2] - m8), e3 = __expf(t0[3] - m8);
        float s4 = e0 + e1 + e2 + e3;
        float s8 = s4 + __shfl_xor(s4, 16, 64);
        float inv = 1.0f / s8;
        uint32_t p01 = pk2f(e0 * inv, e1 * inv);
        uint32_t p23 = pk2f(e2 * inv, e3 * inv);
        uint32_t q01 = (uint32_t)__builtin_amdgcn_ds_bpermute(n16 * 4, (int)p01);
        uint32_t q23 = (uint32_t)__builtin_amdgcn_ds_bpermute(n16 * 4, (int)p23);
        uint32_t q45 = (uint32_t)__builtin_amdgcn_ds_bpermute((n16 + 16) * 4, (int)p01);
        uint32_t q67 = (uint32_t)__builtin_amdgcn_ds_bpermute((n16 + 16) * 4, (int)p23);
        float cw[8] = { bf2f(q01 & 0xffff), bf2f(q01 >> 16),
                        bf2f(q23 & 0xffff), bf2f(q23 >> 16),
                        bf2f(q45 & 0xffff), bf2f(q45 >> 16),
                        bf2f(q67 & 0xffff), bf2f(q67 >> 16) };

        // ---- bank stage: out = sum_k c_k * (Bank_k . feat); frags from LDS ----
        FragU bf_;
        bf_.u[0] = pk2f(fa.x, fa.y); bf_.u[1] = pk2f(fa.z, fa.w);
        bf_.u[2] = pk2f(fb.x, fb.y); bf_.u[3] = pk2f(fb.z, fb.w);

        f32x4 o0 = {0.f, 0.f, 0.f, 0.f}, o1 = {0.f, 0.f, 0.f, 0.f};
        #pragma unroll
        for (int k = 0; k < 8; ++k) {
            f32x4 z = {0.f, 0.f, 0.f, 0.f};
            f32x4 u0 = MF(LDS_F(k * 512),       bf_.v, z);
            f32x4 u1 = MF(LDS_F(k * 512 + 256), bf_.v, z);
            #pragma unroll
            for (int r = 0; r < 4; ++r) {
                o0[r] += cw[k] * u0[r];
                o1[r] += cw[k] * u1[r];
            }
        }

        float* orow = out + n * 32;
        *(float4*)(orow + 4 * g)      = make_float4(o0[0], o0[1], o0[2], o0[3]);
        *(float4*)(orow + 16 + 4 * g) = make_float4(o1[0], o1[1], o1[2], o1[3]);
    }
    #undef LDS_F
}

extern "C" void kernel_launch(void* const* d_in, const int* in_sizes, int n_in,
                              void* d_out, int out_size, void* d_ws, size_t ws_size,
                              hipStream_t stream)
{
    const float* rel = (const float*)d_in[0];
    const float* feat = (const float*)d_in[1];
    WPf wp;
    for (int i = 0; i < 13; ++i) wp.p[i] = (const float*)d_in[2 + i];
    uint32_t* ws = (uint32_t*)d_ws;
    float* out = (float*)d_out;

    const int npts = in_sizes[0] / 60;                 // 262144
    const int nblocks = npts / (16 * IT * 4);          // 1024

    hipLaunchKernelGGL(pc_prep, dim3(40), dim3(256), 0, stream, wp, ws);
    hipLaunchKernelGGL(pc_main, dim3(nblocks), dim3(256), 0, stream, rel, feat, ws, out);
}

// Round 7
// 161.107 us; speedup vs baseline: 1.3852x; 1.3852x over previous
//
#include <hip/hip_runtime.h>
#include <stdint.h>

// All I/O fp32. MFMA bf16: weights as A-operand (A[m=out][k]), activations as
// B (B[k][n=point]); next layer's weights pre-permuted along input dim
// (P(k)=4*(k>>3)+(k&3)+16*((k>>2)&1)) so layer->layer handoff is in-lane packs.
// R7 = R5 (all frags in LDS, biases VGPR; 42 us) + input software-pipelining
// (iter i+1 loads issued before iter i chain) + launch_bounds(256,4).
// R6 lesson: do NOT hold the 13 chain frags in named VGPRs -> scratch spill
// (WRITE_SIZE 32->84 MB). LDS frag reads are fine; the exposed latency was the
// per-iteration *global input* loads, which prefetching hides.

typedef __attribute__((ext_vector_type(8))) __bf16 bf16x8;
typedef __attribute__((ext_vector_type(4))) float f32x4;

union FragU { uint32_t u[4]; bf16x8 v; uint4 q; };

__device__ __forceinline__ unsigned short f2bf(float f) {
    union { float f; uint32_t i; } v; v.f = f;
    return (unsigned short)((v.i + 0x7FFFu + ((v.i >> 16) & 1u)) >> 16); // RTNE (prep only)
}
__device__ __forceinline__ float bf2f(uint32_t u16) {
    union { uint32_t i; float f; } v; v.i = u16 << 16; return v.f;
}
// fast pack: lo16 = bf16(x), hi16 = bf16(y); round-half-up (3 VALU)
__device__ __forceinline__ uint32_t pk2f(float x, float y) {
    union { float f; uint32_t i; } a, b; a.f = x; b.f = y;
    return __builtin_amdgcn_perm(b.i + 0x8000u, a.i + 0x8000u, 0x07060302u);
}
__device__ __forceinline__ int permK(int k) {
    return 4 * (k >> 3) + (k & 3) + 16 * ((k >> 2) & 1);
}
__device__ __forceinline__ f32x4 MF(bf16x8 a, bf16x8 b, f32x4 c) {
    return __builtin_amdgcn_mfma_f32_16x16x32_bf16(a, b, c, 0, 0, 0);
}

// ws dword layout (10240 dwords):
//   [0,1024)    layer0 A-frags  [chunk(2)][tile(2)][lane(64)][dw(4)]  (K=60 pad 64)
//   [1024,3072) layers1-4 A     [L(4)][tile(2)][lane][dw]             (perm k)
//   [3072,3328) layer5 A        [lane][dw]                            (perm k, m>=8 zero)
//   [3328,7424) bank A          [k(8)][tile(2)][lane][dw]
//   [7424,9984) bias L0-4 fp32  [L(5)][tile(2)][lane][r(4)]
//   [9984,10240) bias L5 fp32   [lane][r]                             (m>=8 zero)

struct WPf { const float* p[13]; };

__global__ void pc_prep(WPf wp, uint32_t* __restrict__ ws) {
    int idx = blockIdx.x * blockDim.x + threadIdx.x;
    if (idx >= 10240) return;
    if (idx < 7424) {
        int layer, t, chunk = 0, lane, d; const float* w; bool perm;
        int r = idx;
        if (r < 1024) { chunk = r >> 9; r &= 511; t = r >> 8; r &= 255; lane = r >> 2; d = r & 3;
                        layer = 0; w = wp.p[0]; perm = false; }
        else if (r < 3072) { r -= 1024; layer = 1 + (r >> 9); r &= 511; t = r >> 8; r &= 255;
                             lane = r >> 2; d = r & 3; w = wp.p[2 * layer]; perm = true; }
        else if (r < 3328) { r -= 3072; layer = 5; t = 0; lane = r >> 2; d = r & 3;
                             w = wp.p[10]; perm = true; }
        else { r -= 3328; int bk = r >> 9; r &= 511; t = r >> 8; r &= 255; lane = r >> 2; d = r & 3;
               layer = -1; w = wp.p[12] + bk * 1024; perm = false; }
        int gq = lane >> 4, m = t * 16 + (lane & 15);
        uint32_t o = 0;
        #pragma unroll
        for (int e = 0; e < 2; ++e) {
            int kf = 8 * gq + 2 * d + e;
            float v = 0.f;
            if (layer == -1) {
                v = w[kf * 32 + m];                       // bank: A[m=o][k=i] = bank[k][i*32+o]
            } else {
                int ks = perm ? permK(kf) : (chunk * 32 + kf);
                if (layer == 0)      { if (ks < 60) v = w[ks * 32 + m]; }
                else if (layer == 5) { if (m < 8)   v = w[ks * 8 + m]; }
                else                 v = w[ks * 32 + m];  // A[m][k] = W[P(k)][m]
            }
            o |= ((uint32_t)f2bf(v)) << (16 * e);
        }
        ws[idx] = o;
    } else if (idx < 9984) {
        int r = idx - 7424; int L = r >> 9; r &= 511; int t = r >> 8; r &= 255;
        int lane = r >> 2, rr = r & 3;
        ((float*)ws)[idx] = wp.p[2 * L + 1][t * 16 + 4 * (lane >> 4) + rr];
    } else {
        int r = idx - 9984; int lane = r >> 2, rr = r & 3;
        int m = 4 * (lane >> 4) + rr;
        ((float*)ws)[idx] = (m < 8) ? wp.p[11][m] : 0.f;
    }
}

#define IT 2   // 16 pts/wave-iter * 2 iters * 4 waves = 128 pts/block; 2048 blocks

__global__ __launch_bounds__(256, 4) void pc_main(
    const float* __restrict__ rel, const float* __restrict__ feat,
    const uint32_t* __restrict__ wsu, float* __restrict__ out)
{
    __shared__ __align__(16) uint32_t W[7424];   // 29 KB: all weight frags
    {
        uint4* s4 = (uint4*)W;
        const uint4* g4 = (const uint4*)wsu;
        for (int i = threadIdx.x; i < 1856; i += 256) s4[i] = g4[i];
    }
    __syncthreads();

    const int lane = threadIdx.x & 63;
    const int wv = threadIdx.x >> 6;
    const int g = lane >> 4;
    const int n16 = lane & 15;

    // biases VGPR-resident (44 regs), read from global (L2-hot) once per wave
    const float* bw = (const float*)wsu;
    f32x4 Bi[5][2], Bi5;
    #pragma unroll
    for (int L = 0; L < 5; ++L)
        #pragma unroll
        for (int t = 0; t < 2; ++t) {
            float4 b = ((const float4*)(bw + 7424 + L * 512 + t * 256))[lane];
            Bi[L][t][0] = b.x; Bi[L][t][1] = b.y; Bi[L][t][2] = b.z; Bi[L][t][3] = b.w;
        }
    {
        float4 b = ((const float4*)(bw + 9984))[lane];
        Bi5[0] = b.x; Bi5[1] = b.y; Bi5[2] = b.z; Bi5[3] = b.w;
    }

    const size_t pt0 = (size_t)(blockIdx.x * 4 + wv) * (16 * IT);

    #define LDF(off) ({ FragU _f; _f.q = ((const uint4*)(W + (off)))[lane]; _f.v; })

    // ---- software-pipelined input loads: issue iter-0 loads now ----
    float4 ra, rb, rc, rd, fa, fb;
    {
        const size_t n = pt0 + n16;
        const float* rrow = rel + n * 60;
        ra = *(const float4*)(rrow + 8 * g);
        rb = *(const float4*)(rrow + 8 * g + 4);
        rc = *(const float4*)(rrow + 32 + 8 * g);
        rd = make_float4(0.f, 0.f, 0.f, 0.f);
        if (g < 3) rd = *(const float4*)(rrow + 36 + 8 * g);
        const float* frow = feat + n * 32 + 8 * g;
        fa = *(const float4*)frow;
        fb = *(const float4*)(frow + 4);
    }

    #pragma unroll
    for (int it = 0; it < IT; ++it) {
        const size_t n = pt0 + (size_t)it * 16 + n16;

        // consume current inputs into frags
        FragU b0, b1, bf_;
        b0.u[0] = pk2f(ra.x, ra.y); b0.u[1] = pk2f(ra.z, ra.w);
        b0.u[2] = pk2f(rb.x, rb.y); b0.u[3] = pk2f(rb.z, rb.w);
        b1.u[0] = pk2f(rc.x, rc.y); b1.u[1] = pk2f(rc.z, rc.w);
        b1.u[2] = pk2f(rd.x, rd.y); b1.u[3] = pk2f(rd.z, rd.w);
        bf_.u[0] = pk2f(fa.x, fa.y); bf_.u[1] = pk2f(fa.z, fa.w);
        bf_.u[2] = pk2f(fb.x, fb.y); bf_.u[3] = pk2f(fb.z, fb.w);

        // ---- prefetch next iteration's inputs (overlaps the chain below) ----
        if (it + 1 < IT) {
            const size_t n2 = n + 16;
            const float* rrow2 = rel + n2 * 60;
            ra = *(const float4*)(rrow2 + 8 * g);
            rb = *(const float4*)(rrow2 + 8 * g + 4);
            rc = *(const float4*)(rrow2 + 32 + 8 * g);
            rd = make_float4(0.f, 0.f, 0.f, 0.f);
            if (g < 3) rd = *(const float4*)(rrow2 + 36 + 8 * g);
            const float* frow2 = feat + n2 * 32 + 8 * g;
            fa = *(const float4*)frow2;
            fb = *(const float4*)(frow2 + 4);
        }

        // ---- layer 0 ----
        f32x4 t0 = Bi[0][0], t1 = Bi[0][1];
        t0 = MF(LDF(0),   b0.v, t0); t1 = MF(LDF(256), b0.v, t1);
        t0 = MF(LDF(512), b1.v, t0); t1 = MF(LDF(768), b1.v, t1);

        // ---- layers 1..4 ----
        #pragma unroll
        for (int L = 0; L < 4; ++L) {
            FragU bx;
            #pragma unroll
            for (int r = 0; r < 4; ++r) {
                t0[r] = fmaxf(t0[r], 0.01f * t0[r]);
                t1[r] = fmaxf(t1[r], 0.01f * t1[r]);
            }
            bx.u[0] = pk2f(t0[0], t0[1]); bx.u[1] = pk2f(t0[2], t0[3]);
            bx.u[2] = pk2f(t1[0], t1[1]); bx.u[3] = pk2f(t1[2], t1[3]);
            t0 = MF(LDF(1024 + L * 512),       bx.v, Bi[L + 1][0]);
            t1 = MF(LDF(1024 + L * 512 + 256), bx.v, Bi[L + 1][1]);
        }

        // ---- layer 5 (32->8) ----
        {
            FragU bx;
            #pragma unroll
            for (int r = 0; r < 4; ++r) {
                t0[r] = fmaxf(t0[r], 0.01f * t0[r]);
                t1[r] = fmaxf(t1[r], 0.01f * t1[r]);
            }
            bx.u[0] = pk2f(t0[0], t0[1]); bx.u[1] = pk2f(t0[2], t0[3]);
            bx.u[2] = pk2f(t1[0], t1[1]); bx.u[3] = pk2f(t1[2], t1[3]);
            t0 = MF(LDF(3072), bx.v, Bi5);   // logits m0..3 in g=0, m4..7 in g=1
        }

        // ---- softmax over 8 (lane pair n16 / n16+16 via xor-16) ----
        float m4 = fmaxf(fmaxf(t0[0], t0[1]), fmaxf(t0[2], t0[3]));
        float m8 = fmaxf(m4, __shfl_xor(m4, 16, 64));
        float e0 = __expf(t0[0] - m8), e1 = __expf(t0[1] - m8);
        float e2 = __expf(t0[2] - m8), e3 = __expf(t0[3] - m8);
        float s4 = e0 + e1 + e2 + e3;
        float s8 = s4 + __shfl_xor(s4, 16, 64);
        float inv = 1.0f / s8;
        uint32_t p01 = pk2f(e0 * inv, e1 * inv);
        uint32_t p23 = pk2f(e2 * inv, e3 * inv);
        uint32_t q01 = (uint32_t)__builtin_amdgcn_ds_bpermute(n16 * 4, (int)p01);
        uint32_t q23 = (uint32_t)__builtin_amdgcn_ds_bpermute(n16 * 4, (int)p23);
        uint32_t q45 = (uint32_t)__builtin_amdgcn_ds_bpermute((n16 + 16) * 4, (int)p01);
        uint32_t q67 = (uint32_t)__builtin_amdgcn_ds_bpermute((n16 + 16) * 4, (int)p23);
        float cw[8] = { bf2f(q01 & 0xffff), bf2f(q01 >> 16),
                        bf2f(q23 & 0xffff), bf2f(q23 >> 16),
                        bf2f(q45 & 0xffff), bf2f(q45 >> 16),
                        bf2f(q67 & 0xffff), bf2f(q67 >> 16) };

        // ---- bank stage: out = sum_k c_k * (Bank_k . feat) ----
        f32x4 o0 = {0.f, 0.f, 0.f, 0.f}, o1 = {0.f, 0.f, 0.f, 0.f};
        #pragma unroll
        for (int k = 0; k < 8; ++k) {
            f32x4 z = {0.f, 0.f, 0.f, 0.f};
            f32x4 u0 = MF(LDF(3328 + k * 512),       bf_.v, z);
            f32x4 u1 = MF(LDF(3328 + k * 512 + 256), bf_.v, z);
            #pragma unroll
            for (int r = 0; r < 4; ++r) {
                o0[r] += cw[k] * u0[r];
                o1[r] += cw[k] * u1[r];
            }
        }

        float* orow = out + n * 32;
        *(float4*)(orow + 4 * g)      = make_float4(o0[0], o0[1], o0[2], o0[3]);
        *(float4*)(orow + 16 + 4 * g) = make_float4(o1[0], o1[1], o1[2], o1[3]);
    }
    #undef LDF
}

extern "C" void kernel_launch(void* const* d_in, const int* in_sizes, int n_in,
                              void* d_out, int out_size, void* d_ws, size_t ws_size,
                              hipStream_t stream)
{
    const float* rel = (const float*)d_in[0];
    const float* feat = (const float*)d_in[1];
    WPf wp;
    for (int i = 0; i < 13; ++i) wp.p[i] = (const float*)d_in[2 + i];
    uint32_t* ws = (uint32_t*)d_ws;
    float* out = (float*)d_out;

    const int npts = in_sizes[0] / 60;                 // 262144
    const int nblocks = npts / (16 * IT * 4);          // 2048

    hipLaunchKernelGGL(pc_prep, dim3(40), dim3(256), 0, stream, wp, ws);
    hipLaunchKernelGGL(pc_main, dim3(nblocks), dim3(256), 0, stream, rel, feat, ws, out);
}